// Round 1
// baseline (88.929 us; speedup 1.0000x reference)
//
#include <hip/hip_runtime.h>

#define NQ 4
#define DIM 16
#define NUM_LAYERS 4

struct cplx { float x, y; };
__device__ inline cplx cmul(cplx a, cplx b) { return { a.x*b.x - a.y*b.y, a.x*b.y + a.y*b.x }; }
__device__ inline cplx cadd(cplx a, cplx b) { return { a.x + b.x, a.y + b.y }; }

__global__ __launch_bounds__(256) void vqc_kernel(
    const int* __restrict__ x1, const int* __restrict__ x2,
    const float* __restrict__ wa, const float* __restrict__ wb,
    const float* __restrict__ scal_a, const float* __restrict__ scal_b,
    float* __restrict__ out, int batch)
{
    __shared__ float4 table[DIM];

    if (threadIdx.x < DIM) {
        const int tid = threadIdx.x;
        cplx s[DIM];
        #pragma unroll
        for (int k = 0; k < DIM; k++) s[k] = { 0.f, 0.f };
        s[tid].x = 1.f;

        #pragma unroll
        for (int layer = 0; layer < NUM_LAYERS; layer++) {
            // --- Rot gate on each wire ---
            #pragma unroll
            for (int wire = 0; wire < NQ; wire++) {
                // w_per_wire: wire 0,1 -> weights_a[:,0],[:,1]; wire 2,3 -> weights_b[:,0],[:,1]
                const float* wp = (wire < 2) ? (wa + layer * 6 + wire * 3)
                                             : (wb + layer * 6 + (wire - 2) * 3);
                const float phi = wp[0], theta = wp[1], omega = wp[2];
                const float ct = cosf(0.5f * theta), st = sinf(0.5f * theta);
                const float aa = 0.5f * (phi + omega);
                const float bb = 0.5f * (phi - omega);
                const float ca = cosf(aa), sa = sinf(aa);
                const float cb = cosf(bb), sb = sinf(bb);
                // U = [[e^{-i a} c, -e^{+i b} s], [e^{-i b} s, e^{+i a} c]]
                const cplx U00 = {  ct * ca, -ct * sa };
                const cplx U01 = { -st * cb, -st * sb };
                const cplx U10 = {  st * cb, -st * sb };
                const cplx U11 = {  ct * ca,  ct * sa };
                const int mask = 8 >> wire;  // bit (3 - wire), MSB-first
                #pragma unroll
                for (int i = 0; i < DIM; i++) {
                    if (i & mask) continue;
                    const cplx a0 = s[i];
                    const cplx a1 = s[i | mask];
                    s[i]        = cadd(cmul(U00, a0), cmul(U01, a1));
                    s[i | mask] = cadd(cmul(U10, a0), cmul(U11, a1));
                }
            }
            // --- CNOTs: (c,t) = (0,1),(2,3),(0,2),(0,3) — conditional swap ---
            const int cn_c[4] = { 0, 2, 0, 0 };
            const int cn_t[4] = { 1, 3, 2, 3 };
            #pragma unroll
            for (int g = 0; g < 4; g++) {
                const int cmask = 8 >> cn_c[g];
                const int tmask = 8 >> cn_t[g];
                #pragma unroll
                for (int i = 0; i < DIM; i++) {
                    if ((i & cmask) && !(i & tmask)) {
                        const cplx tmp = s[i];
                        s[i] = s[i | tmask];
                        s[i | tmask] = tmp;
                    }
                }
            }
        }

        float probs[DIM];
        #pragma unroll
        for (int k = 0; k < DIM; k++) probs[k] = s[k].x * s[k].x + s[k].y * s[k].y;

        const float scale[4] = { scal_a[0], scal_a[1], scal_b[0], scal_b[1] };
        float q[4];
        #pragma unroll
        for (int w = 0; w < 4; w++) {
            const int m = 8 >> w;
            float e = 0.f;
            #pragma unroll
            for (int k = 0; k < DIM; k++) e += (k & m) ? -probs[k] : probs[k];
            q[w] = (e + 1.f) * 0.5f * scale[w];
        }
        table[tid] = make_float4(q[0], q[1], q[2], q[3]);
    }
    __syncthreads();

    // --- gather phase: 2 batch elements per thread ---
    const int pair = blockIdx.x * blockDim.x + threadIdx.x;
    const int b = pair * 2;
    if (b < batch) {
        const int4 xa = ((const int4*)x1)[pair];  // x1[b][0], x1[b][1], x1[b+1][0], x1[b+1][1]
        const int4 xb = ((const int4*)x2)[pair];
        const int i0 = xa.x * 8 + xa.y * 4 + xb.x * 2 + xb.y;
        const int i1 = xa.z * 8 + xa.w * 4 + xb.z * 2 + xb.w;
        float4* o = (float4*)out;
        o[b]     = table[i0];
        o[b + 1] = table[i1];
    }
}

extern "C" void kernel_launch(void* const* d_in, const int* in_sizes, int n_in,
                              void* d_out, int out_size, void* d_ws, size_t ws_size,
                              hipStream_t stream) {
    const int*   x1     = (const int*)d_in[0];
    const int*   x2     = (const int*)d_in[1];
    const float* wa     = (const float*)d_in[2];
    const float* wb     = (const float*)d_in[3];
    const float* scal_a = (const float*)d_in[4];
    const float* scal_b = (const float*)d_in[5];
    float* out = (float*)d_out;

    const int batch = in_sizes[0] / 2;            // x1 is (BATCH, 2)
    const int pairs = batch / 2;                  // 2 batch elements per thread
    const int block = 256;
    const int grid  = (pairs + block - 1) / block;

    vqc_kernel<<<grid, block, 0, stream>>>(x1, x2, wa, wb, scal_a, scal_b, out, batch);
}

// Round 3
// 83.804 us; speedup vs baseline: 1.0611x; 1.0611x over previous
//
#include <hip/hip_runtime.h>

#define NQ 4
#define DIM 16
#define NUM_LAYERS 4
#define NGATES 16   // NUM_LAYERS * NQ

struct cplx { float x, y; };
__device__ inline cplx cmul(cplx a, cplx b) { return { a.x*b.x - a.y*b.y, a.x*b.y + a.y*b.x }; }
__device__ inline cplx cadd(cplx a, cplx b) { return { a.x + b.x, a.y + b.y }; }

// Single kernel (no cross-kernel d_ws dependency — R2 showed that races under
// graph replay). Per block: phase 1 computes 96 trig values in parallel
// (threads 0..95, HW __sinf/__cosf); phase 2 evolves the 16 basis states
// (threads 0..15, U entries from LDS); phase 3 all 256 threads gather.
__global__ __launch_bounds__(256) void vqc_kernel(
    const int* __restrict__ x1, const int* __restrict__ x2,
    const float* __restrict__ wa, const float* __restrict__ wb,
    const float* __restrict__ scal_a, const float* __restrict__ scal_b,
    float4* __restrict__ out, int batch)
{
    __shared__ float trig[NGATES][6];   // ct, st, ca, sa, cb, sb per gate
    __shared__ float4 table[DIM];

    const int t = threadIdx.x;

    // --- phase 1: trig, one value per thread ---
    if (t < NGATES * 6) {
        const int g = t / 6, slot = t % 6;
        const int layer = g >> 2, wire = g & 3;
        // w_per_wire: wires 0,1 -> weights_a[:,0],[:,1]; wires 2,3 -> weights_b[:,0],[:,1]
        const float* wp = (wire < 2) ? (wa + layer * 6 + wire * 3)
                                     : (wb + layer * 6 + (wire - 2) * 3);
        const float phi = wp[0], theta = wp[1], omega = wp[2];
        const float arg = (slot < 2) ? 0.5f * theta
                        : (slot < 4) ? 0.5f * (phi + omega)
                                     : 0.5f * (phi - omega);
        trig[g][slot] = (slot & 1) ? __sinf(arg) : __cosf(arg);
    }
    __syncthreads();

    // --- phase 2: evolve 16 basis states, one per lane ---
    if (t < DIM) {
        cplx s[DIM];
        #pragma unroll
        for (int k = 0; k < DIM; k++) s[k] = { 0.f, 0.f };
        s[t].x = 1.f;

        #pragma unroll
        for (int layer = 0; layer < NUM_LAYERS; layer++) {
            #pragma unroll
            for (int wire = 0; wire < NQ; wire++) {
                const int g = layer * 4 + wire;
                const float ct = trig[g][0], st = trig[g][1];
                const float ca = trig[g][2], sa = trig[g][3];
                const float cb = trig[g][4], sb = trig[g][5];
                // U = [[e^{-i a} c, -e^{+i b} s], [e^{-i b} s, e^{+i a} c]]
                const cplx U00 = {  ct * ca, -ct * sa };
                const cplx U01 = { -st * cb, -st * sb };
                const cplx U10 = {  st * cb, -st * sb };
                const cplx U11 = {  ct * ca,  ct * sa };
                const int mask = 8 >> wire;   // wire w acts on bit (3-w), MSB-first
                #pragma unroll
                for (int i = 0; i < DIM; i++) {
                    if (i & mask) continue;
                    const cplx a0 = s[i];
                    const cplx a1 = s[i | mask];
                    s[i]        = cadd(cmul(U00, a0), cmul(U01, a1));
                    s[i | mask] = cadd(cmul(U10, a0), cmul(U11, a1));
                }
            }
            // CNOTs (c,t) = (0,1),(2,3),(0,2),(0,3): conditional swap (involution)
            const int cn_c[4] = { 0, 2, 0, 0 };
            const int cn_t[4] = { 1, 3, 2, 3 };
            #pragma unroll
            for (int gidx = 0; gidx < 4; gidx++) {
                const int cmask = 8 >> cn_c[gidx];
                const int tmask = 8 >> cn_t[gidx];
                #pragma unroll
                for (int i = 0; i < DIM; i++) {
                    if ((i & cmask) && !(i & tmask)) {
                        const cplx tmp = s[i];
                        s[i] = s[i | tmask];
                        s[i | tmask] = tmp;
                    }
                }
            }
        }

        float probs[DIM];
        #pragma unroll
        for (int k = 0; k < DIM; k++) probs[k] = s[k].x * s[k].x + s[k].y * s[k].y;

        const float scale[4] = { scal_a[0], scal_a[1], scal_b[0], scal_b[1] };
        float q[4];
        #pragma unroll
        for (int w = 0; w < 4; w++) {
            const int m = 8 >> w;   // Z on wire w: sign flips when bit (3-w) set
            float e = 0.f;
            #pragma unroll
            for (int k = 0; k < DIM; k++) e += (k & m) ? -probs[k] : probs[k];
            q[w] = (e + 1.f) * 0.5f * scale[w];
        }
        table[t] = make_float4(q[0], q[1], q[2], q[3]);
    }
    __syncthreads();

    // --- phase 3: gather, 2 batch elements per thread ---
    const int pair = blockIdx.x * blockDim.x + threadIdx.x;
    const int b = pair * 2;
    if (b < batch) {
        const int4 xa = ((const int4*)x1)[pair];  // x1[b][0..1], x1[b+1][0..1]
        const int4 xb = ((const int4*)x2)[pair];
        const int i0 = xa.x * 8 + xa.y * 4 + xb.x * 2 + xb.y;
        const int i1 = xa.z * 8 + xa.w * 4 + xb.z * 2 + xb.w;
        out[b]     = table[i0];
        out[b + 1] = table[i1];
    }
}

extern "C" void kernel_launch(void* const* d_in, const int* in_sizes, int n_in,
                              void* d_out, int out_size, void* d_ws, size_t ws_size,
                              hipStream_t stream) {
    const int*   x1     = (const int*)d_in[0];
    const int*   x2     = (const int*)d_in[1];
    const float* wa     = (const float*)d_in[2];
    const float* wb     = (const float*)d_in[3];
    const float* scal_a = (const float*)d_in[4];
    const float* scal_b = (const float*)d_in[5];
    float4* out = (float4*)d_out;

    const int batch = in_sizes[0] / 2;   // x1 is (BATCH, 2)
    const int pairs = batch / 2;         // 2 batch elements per thread
    const int block = 256;
    const int grid  = (pairs + block - 1) / block;

    vqc_kernel<<<grid, block, 0, stream>>>(x1, x2, wa, wb, scal_a, scal_b, out, batch);
}